// Round 9
// baseline (555.434 us; speedup 1.0000x reference)
//
#include <hip/hip_runtime.h>

// ZBL repulsion energy:
//   per pair p: d = |r_ij[p]|; a = z^sp(a_pow); a_ij = (a[i]+a[j])*sp(a_div)
//   screening = sum_k c_k * exp(-sp(e_k)*a_ij*d)   (c_k = L1-normalized softplus)
//   contrib = z_i*z_j/d * screening -> segment_sum idx_i -> segment_sum idx_m -> *0.5
//
// ROUND-6 LESSON: a strictly ws_size-bounded 2MB write to d_ws STILL produced
// the "first call OK, later calls output==0" signature (same as the round-2
// 6MB overrun). Hypothesis: d_ws aliases the harness's pristine-input region
// on this 276MB-input problem. This version therefore touches d_ws NOT AT ALL:
// pairs accumulate into a per-block LDS molecule table (n_mol*4 = 20KB) and
// flush with global atomics directly into d_out. Only d_out is ever written.

__device__ __forceinline__ float d_softplus(float x) {
    return log1pf(__expf(x));
}

struct ZblParams { float sp_div, c0, c1, c2, c3, e0, e1, e2, e3; };

__device__ __forceinline__ ZblParams zbl_load_params(
    const float* __restrict__ a_div,
    const float* __restrict__ co,
    const float* __restrict__ ex)
{
    ZblParams P;
    P.sp_div = d_softplus(a_div[0]);
    float c0 = d_softplus(co[0]);
    float c1 = d_softplus(co[1]);
    float c2 = d_softplus(co[2]);
    float c3 = d_softplus(co[3]);
    float cinv = 1.0f / (c0 + c1 + c2 + c3);  // softplus >= 0 -> L1 norm == sum
    P.c0 = c0 * cinv; P.c1 = c1 * cinv; P.c2 = c2 * cinv; P.c3 = c3 * cinv;
    P.e0 = d_softplus(ex[0]);
    P.e1 = d_softplus(ex[1]);
    P.e2 = d_softplus(ex[2]);
    P.e3 = d_softplus(ex[3]);
    return P;
}

// z values are integers 1..99 used as floats -> z^p has <=100 distinct values.
#define PTAB_N 100

__device__ __forceinline__ float zbl_pair_val(
    float x, float y, float zc, float zi, float zj,
    const float* __restrict__ ptab, const ZblParams& P)
{
    int ki = (int)zi; ki = ki < 0 ? 0 : (ki >= PTAB_N ? PTAB_N - 1 : ki);
    int kj = (int)zj; kj = kj < 0 ? 0 : (kj >= PTAB_N ? PTAB_N - 1 : kj);
    float ai = ptab[ki];
    float aj = ptab[kj];
    float d = sqrtf(x * x + y * y + zc * zc);
    float aijd = (ai + aj) * P.sp_div * d;
    float scr = P.c0 * __expf(-P.e0 * aijd)
              + P.c1 * __expf(-P.e1 * aijd)
              + P.c2 * __expf(-P.e2 * aijd)
              + P.c3 * __expf(-P.e3 * aijd);
    return zi * zj / d * scr;
}

// ---------------- kernel 0: zero d_out (harness poisons it with 0xAA) -------
__global__ void zbl_zero_out_kernel(float* __restrict__ out, int n_mol) {
    int i = blockIdx.x * blockDim.x + threadIdx.x;
    if (i < n_mol) out[i] = 0.0f;
}

// ---------------- kernel 1: pairs -> per-block LDS molecule accum -> d_out --
extern "C" __global__ void __launch_bounds__(256) zbl_pairs_mol_kernel(
    const float* __restrict__ r_ij,
    const int* __restrict__ idx_i,
    const int* __restrict__ idx_j,
    const float* __restrict__ z,
    const int* __restrict__ idx_m,
    const float* __restrict__ a_pow,
    const float* __restrict__ a_div,
    const float* __restrict__ co,
    const float* __restrict__ ex,
    float* __restrict__ out,
    int n_pairs, int n_mol, int n_atoms)
{
    extern __shared__ float mout[];                 // n_mol floats (20 KB)
    for (int m = threadIdx.x; m < n_mol; m += blockDim.x) mout[m] = 0.0f;
    __shared__ float ptab[PTAB_N];
    {
        float p = d_softplus(a_pow[0]);
        if (threadIdx.x < PTAB_N) ptab[threadIdx.x] = __powf((float)threadIdx.x, p);
    }
    __syncthreads();
    ZblParams P = zbl_load_params(a_div, co, ex);

    const float4* __restrict__ r4 = (const float4*)r_ij;
    const int4*   __restrict__ i4 = (const int4*)idx_i;
    const int4*   __restrict__ j4 = (const int4*)idx_j;

    int nvec = n_pairs >> 2;   // 4 pairs / thread: 3 x float4 + 2 x int4
    int stride = gridDim.x * blockDim.x;
    int tid0 = blockIdx.x * blockDim.x + threadIdx.x;

    for (int t = tid0; t < nvec; t += stride) {
        float4 r0 = r4[3 * t + 0];
        float4 r1 = r4[3 * t + 1];
        float4 r2 = r4[3 * t + 2];
        int4 ii = i4[t];
        int4 jj = j4[t];
        float v0 = zbl_pair_val(r0.x, r0.y, r0.z, z[ii.x], z[jj.x], ptab, P);
        float v1 = zbl_pair_val(r0.w, r1.x, r1.y, z[ii.y], z[jj.y], ptab, P);
        float v2 = zbl_pair_val(r1.z, r1.w, r2.x, z[ii.z], z[jj.z], ptab, P);
        float v3 = zbl_pair_val(r2.y, r2.z, r2.w, z[ii.w], z[jj.w], ptab, P);
        atomicAdd(&mout[idx_m[ii.x]], v0);
        atomicAdd(&mout[idx_m[ii.y]], v1);
        atomicAdd(&mout[idx_m[ii.z]], v2);
        atomicAdd(&mout[idx_m[ii.w]], v3);
    }
    for (int p = (nvec << 2) + tid0; p < n_pairs; p += stride) {
        int i = idx_i[p], j = idx_j[p];
        float v = zbl_pair_val(r_ij[3 * p], r_ij[3 * p + 1], r_ij[3 * p + 2],
                               z[i], z[j], ptab, P);
        atomicAdd(&mout[idx_m[i]], v);
    }
    __syncthreads();
    // flush: one global atomic per (block, nonzero molecule); 0.5 factor here
    for (int m = threadIdx.x; m < n_mol; m += blockDim.x) {
        float v = mout[m];
        if (v != 0.0f) atomicAdd(&out[m], 0.5f * v);
    }
}

extern "C" void kernel_launch(void* const* d_in, const int* in_sizes, int n_in,
                              void* d_out, int out_size, void* d_ws, size_t ws_size,
                              hipStream_t stream) {
    const float* z            = (const float*)d_in[0];
    const float* r_ij         = (const float*)d_in[1];
    const float* a_pow        = (const float*)d_in[2];
    const float* a_div        = (const float*)d_in[3];
    const float* coefficients = (const float*)d_in[4];
    const float* exponents    = (const float*)d_in[5];
    const int*   idx_i        = (const int*)d_in[6];
    const int*   idx_j        = (const int*)d_in[7];
    const int*   idx_m        = (const int*)d_in[8];
    float* out = (float*)d_out;

    int n_atoms = in_sizes[0];
    int n_pairs = in_sizes[6];
    int n_mol   = out_size;

    (void)d_ws; (void)ws_size;  // deliberately unused (see header comment)

    const int threads = 256;
    int blocks_out = (n_mol + threads - 1) / threads;
    zbl_zero_out_kernel<<<blocks_out, threads, 0, stream>>>(out, n_mol);

    // 1024 blocks: 4 blocks/CU resident (20.4 KB LDS each), grid-stride over
    // 4M vec-iterations (~15 each); flush atomics = 1024 * n_mol = 5.1M.
    int blocks_pairs = 1024;
    size_t lds_bytes = (size_t)n_mol * sizeof(float);
    zbl_pairs_mol_kernel<<<blocks_pairs, threads, lds_bytes, stream>>>(
        r_ij, idx_i, idx_j, z, idx_m, a_pow, a_div, coefficients, exponents,
        out, n_pairs, n_mol, n_atoms);
}